// Round 8
// baseline (5101.274 us; speedup 1.0000x reference)
//
#include <hip/hip_runtime.h>
#include <math.h>

#define BB 64
#define SS 512
#define DD 207
#define HH 256
#define NWG 64
#define LDW 676   // wgl row stride (%32==4 -> staggered banks)
#define ROW 260   // wrol row stride
#define AG __HIP_MEMORY_SCOPE_AGENT

// ================= v14: v13 + deep load pipelining (256-VGPR budget) =========
// Same structure/protocol as v13 (fused PhaseB+gh pass; 2 barriers/step).
// LDS (95KB) pins occupancy at 1 WG/CU = 2 waves/SIMD, so the compiler may
// legally use 256 VGPR/thread (2 x 256 = 512 = per-SIMD pool). v13 compiled
// at exactly 128 VGPR (default heuristic) -> only ~8 float4 loads in flight
// -> the 32-load fused pass and 52-load xin pass run as 4-7 serialized
// ~500cy latency batches. Fix: __launch_bounds__(512, 2) + full unroll of the
// fused pass + unroll-8 xin GEMV (dedicated helper; v3 fallback untouched).
#define SROWS 672
#define HOFF  416
#define SLOT  (SROWS * 64)
#define BUF_FLOATS ((size_t)SS * SLOT)
#define FLAG_U32 (64 * 32)
#define STAGE_FLOATS ((size_t)SS * DD * 64)
#define WS_NEED6 ((BUF_FLOATS + FLAG_U32 + STAGE_FLOATS) * sizeof(float))

// ---- v3 fallback layout (round-3 proven path) ----
#define V3_AROWS 928
#define V3_HBASE 416
#define V3_ACT (V3_AROWS * 64)
#define V3_FLAGS (64 * 32)
#define V3_WS_SMALL ((size_t)(V3_ACT + V3_FLAGS) * sizeof(float))
#define V3_WS_FULL  ((size_t)(V3_ACT + V3_FLAGS + STAGE_FLOATS) * sizeof(float))

__device__ __forceinline__ void ast4(float* p, float v) {
    union { float f; unsigned u; } c; c.f = v;
    __hip_atomic_store((unsigned*)p, c.u, __ATOMIC_RELAXED, AG);
}

// 12-row (3 gates x unit u) GEMV partial, NORMAL float4 loads (round-3 shape).
// gr0 = global float4-row base (t*672 + local row), wc0 = weight col base.
__device__ __forceinline__ void run_range6(
    const float4* __restrict__ A4, const float* __restrict__ wgl,
    float* __restrict__ red, int u, int bp, int wc0, int gr0, int len, int slot)
{
    float4 c0 = make_float4(0.f, 0.f, 0.f, 0.f);
    float4 c1 = c0, c2 = c0;
    #pragma unroll 4
    for (int k = 0; k < len; k += 4) {
        float4 a0 = A4[(gr0 + k + 0) * 16 + bp];
        float4 a1 = A4[(gr0 + k + 1) * 16 + bp];
        float4 a2 = A4[(gr0 + k + 2) * 16 + bp];
        float4 a3 = A4[(gr0 + k + 3) * 16 + bp];
        float4 w0 = *(const float4*)&wgl[(0 + u) * LDW + wc0 + k];
        float4 w1 = *(const float4*)&wgl[(4 + u) * LDW + wc0 + k];
        float4 w2 = *(const float4*)&wgl[(8 + u) * LDW + wc0 + k];
        c0.x += a0.x*w0.x + a1.x*w0.y + a2.x*w0.z + a3.x*w0.w;
        c0.y += a0.y*w0.x + a1.y*w0.y + a2.y*w0.z + a3.y*w0.w;
        c0.z += a0.z*w0.x + a1.z*w0.y + a2.z*w0.z + a3.z*w0.w;
        c0.w += a0.w*w0.x + a1.w*w0.y + a2.w*w0.z + a3.w*w0.w;
        c1.x += a0.x*w1.x + a1.x*w1.y + a2.x*w1.z + a3.x*w1.w;
        c1.y += a0.y*w1.x + a1.y*w1.y + a2.y*w1.z + a3.y*w1.w;
        c1.z += a0.z*w1.x + a1.z*w1.y + a2.z*w1.z + a3.z*w1.w;
        c1.w += a0.w*w1.x + a1.w*w1.y + a2.w*w1.z + a3.w*w1.w;
        c2.x += a0.x*w2.x + a1.x*w2.y + a2.x*w2.z + a3.x*w2.w;
        c2.y += a0.y*w2.x + a1.y*w2.y + a2.y*w2.z + a3.y*w2.w;
        c2.z += a0.z*w2.x + a1.z*w2.y + a2.z*w2.z + a3.z*w2.w;
        c2.w += a0.w*w2.x + a1.w*w2.y + a2.w*w2.z + a3.w*w2.w;
    }
    float4* R4 = (float4*)red;
    R4[(slot * 12 + 0 + u) * 16 + bp] = c0;
    R4[(slot * 12 + 4 + u) * 16 + bp] = c1;
    R4[(slot * 12 + 8 + u) * 16 + bp] = c2;
}

// deep-pipelined variant for the 256-VGPR persist kernel (unroll 8 -> up to
// 32 A-loads hoistable per window). Same math/layout as run_range6.
__device__ __forceinline__ void run_rangeX(
    const float4* __restrict__ A4, const float* __restrict__ wgl,
    float* __restrict__ red, int u, int bp, int wc0, int gr0, int len, int slot)
{
    float4 c0 = make_float4(0.f, 0.f, 0.f, 0.f);
    float4 c1 = c0, c2 = c0;
    #pragma unroll 8
    for (int k = 0; k < len; k += 4) {
        float4 a0 = A4[(gr0 + k + 0) * 16 + bp];
        float4 a1 = A4[(gr0 + k + 1) * 16 + bp];
        float4 a2 = A4[(gr0 + k + 2) * 16 + bp];
        float4 a3 = A4[(gr0 + k + 3) * 16 + bp];
        float4 w0 = *(const float4*)&wgl[(0 + u) * LDW + wc0 + k];
        float4 w1 = *(const float4*)&wgl[(4 + u) * LDW + wc0 + k];
        float4 w2 = *(const float4*)&wgl[(8 + u) * LDW + wc0 + k];
        c0.x += a0.x*w0.x + a1.x*w0.y + a2.x*w0.z + a3.x*w0.w;
        c0.y += a0.y*w0.x + a1.y*w0.y + a2.y*w0.z + a3.y*w0.w;
        c0.z += a0.z*w0.x + a1.z*w0.y + a2.z*w0.z + a3.z*w0.w;
        c0.w += a0.w*w0.x + a1.w*w0.y + a2.w*w0.z + a3.w*w0.w;
        c1.x += a0.x*w1.x + a1.x*w1.y + a2.x*w1.z + a3.x*w1.w;
        c1.y += a0.y*w1.x + a1.y*w1.y + a2.y*w1.z + a3.y*w1.w;
        c1.z += a0.z*w1.x + a1.z*w1.y + a2.z*w1.z + a3.z*w1.w;
        c1.w += a0.w*w1.x + a1.w*w1.y + a2.w*w1.z + a3.w*w1.w;
        c2.x += a0.x*w2.x + a1.x*w2.y + a2.x*w2.z + a3.x*w2.w;
        c2.y += a0.y*w2.x + a1.y*w2.y + a2.y*w2.z + a3.y*w2.w;
        c2.z += a0.z*w2.x + a1.z*w2.y + a2.z*w2.z + a3.z*w2.w;
        c2.w += a0.w*w2.x + a1.w*w2.y + a2.w*w2.z + a3.w*w2.w;
    }
    float4* R4 = (float4*)red;
    R4[(slot * 12 + 0 + u) * 16 + bp] = c0;
    R4[(slot * 12 + 4 + u) * 16 + bp] = c1;
    R4[(slot * 12 + 8 + u) * 16 + bp] = c2;
}

__global__ __launch_bounds__(256) void rnn_init6(float* __restrict__ ws) {
    int i = blockIdx.x * blockDim.x + threadIdx.x;
    // zero slot-0 h rows (h_0 = 0)
    for (int idx = i; idx < HH * 64; idx += gridDim.x * blockDim.x)
        ws[HOFF * 64 + idx] = 0.f;
    unsigned* fl = (unsigned*)(ws + BUF_FLOATS);
    for (int idx = i; idx < FLAG_U32; idx += gridDim.x * blockDim.x)
        fl[idx] = 0u;
}

__global__ __launch_bounds__(512, 2) void rnn_persist14(
    const float* __restrict__ x, const float* __restrict__ mask,
    const float* __restrict__ W_ih, const float* __restrict__ W_hh,
    const float* __restrict__ b_ih, const float* __restrict__ b_hh,
    const float* __restrict__ W_ro, const float* __restrict__ b_ro,
    float* __restrict__ ws, float* __restrict__ out)
{
    const int wg = blockIdx.x;
    const int tid = threadIdx.x;
    const int lane = tid & 63;
    const int wv = tid >> 6;          // 0..7

    float* buf = ws;
    unsigned* flags = (unsigned*)(ws + BUF_FLOATS);
    float* stage = ws + BUF_FLOATS + FLAG_U32;

    __shared__ float wgl[12 * LDW];      // 12 gate rows x 676 (cols 414/415 = 0)
    __shared__ float wrol[4 * ROW];      // up to 4 readout rows
    __shared__ float red[16 * 12 * 64];  // slots 0-7 xin partials, 8-15 gh
    __shared__ float redB[32 * 64];      // readout partials (8 waves x 4 rows)
    __shared__ float hloc[4 * 64];       // own hidden units
    __shared__ float bihl[12], bhhl[12], brol[4];

    const int d0 = (207 * wg) / NWG;
    const int d1 = (207 * (wg + 1)) / NWG;
    const int dc = d1 - d0;

    for (int i = tid; i < 12 * LDW; i += 512) {
        int r = i / LDW, c = i - r * LDW;
        int rg = (r >> 2) * 256 + wg * 4 + (r & 3);
        float v = 0.f;
        if (c < 414) v = W_ih[rg * 414 + c];
        else if (c >= 416 && c < 672) v = W_hh[rg * 256 + (c - 416)];
        wgl[i] = v;
    }
    for (int i = tid; i < 4 * 256; i += 512) {
        int dl_ = i >> 8, j = i & 255;
        wrol[dl_ * ROW + j] = (dl_ < dc) ? W_ro[(d0 + dl_) * 256 + j] : 0.f;
    }
    if (tid < 12) {
        int rg = (tid >> 2) * 256 + wg * 4 + (tid & 3);
        bihl[tid] = b_ih[rg];
        bhhl[tid] = b_hh[rg];
    }
    if (tid < 4) brol[tid] = (tid < dc) ? b_ro[d0 + tid] : 0.f;
    if (tid < 256) hloc[tid] = 0.f;
    __syncthreads();

    const float4* A4 = (const float4*)buf;
    const int u  = lane >> 4;
    const int bp = lane & 15;

    const bool have = (tid < dc * 64);
    const int dl = tid >> 6, b = tid & 63;
    const size_t gbase = (size_t)b * (SS * DD) + (d0 + dl);
    float xv_pf = 0.f, mv_pf = 0.f;
    if (have) { xv_pf = x[gbase]; mv_pf = mask[gbase]; }

    unsigned gen = 0;

    for (int t = 0; t < SS; ++t) {
        const int sbase = t * SROWS;        // this step's slot (row units)

        // ---- Fused Phase B + gh: ONE pass over h_t (float4, virgin reads) ----
        // Full unroll: all 32 A-loads visible to the scheduler in one window.
        {
            const int jb = wv * 32;
            const int gr0 = sbase + HOFF + jb;     // h rows (float4 rows)
            const int wc0 = 416 + jb;              // gate weight cols
            float4 c0 = make_float4(0.f, 0.f, 0.f, 0.f);
            float4 c1 = c0, c2 = c0, cR = c0;
            #pragma unroll
            for (int k = 0; k < 32; k += 4) {
                float4 a0 = A4[(gr0 + k + 0) * 16 + bp];
                float4 a1 = A4[(gr0 + k + 1) * 16 + bp];
                float4 a2 = A4[(gr0 + k + 2) * 16 + bp];
                float4 a3 = A4[(gr0 + k + 3) * 16 + bp];
                float4 w0 = *(const float4*)&wgl[(0 + u) * LDW + wc0 + k];
                float4 w1 = *(const float4*)&wgl[(4 + u) * LDW + wc0 + k];
                float4 w2 = *(const float4*)&wgl[(8 + u) * LDW + wc0 + k];
                float4 wR = *(const float4*)&wrol[u * ROW + jb + k];
                c0.x += a0.x*w0.x + a1.x*w0.y + a2.x*w0.z + a3.x*w0.w;
                c0.y += a0.y*w0.x + a1.y*w0.y + a2.y*w0.z + a3.y*w0.w;
                c0.z += a0.z*w0.x + a1.z*w0.y + a2.z*w0.z + a3.z*w0.w;
                c0.w += a0.w*w0.x + a1.w*w0.y + a2.w*w0.z + a3.w*w0.w;
                c1.x += a0.x*w1.x + a1.x*w1.y + a2.x*w1.z + a3.x*w1.w;
                c1.y += a0.y*w1.x + a1.y*w1.y + a2.y*w1.z + a3.y*w1.w;
                c1.z += a0.z*w1.x + a1.z*w1.y + a2.z*w1.z + a3.z*w1.w;
                c1.w += a0.w*w1.x + a1.w*w1.y + a2.w*w1.z + a3.w*w1.w;
                c2.x += a0.x*w2.x + a1.x*w2.y + a2.x*w2.z + a3.x*w2.w;
                c2.y += a0.y*w2.x + a1.y*w2.y + a2.y*w2.z + a3.y*w2.w;
                c2.z += a0.z*w2.x + a1.z*w2.y + a2.z*w2.z + a3.z*w2.w;
                c2.w += a0.w*w2.x + a1.w*w2.y + a2.w*w2.z + a3.w*w2.w;
                cR.x += a0.x*wR.x + a1.x*wR.y + a2.x*wR.z + a3.x*wR.w;
                cR.y += a0.y*wR.x + a1.y*wR.y + a2.y*wR.z + a3.y*wR.w;
                cR.z += a0.z*wR.x + a1.z*wR.y + a2.z*wR.z + a3.z*wR.w;
                cR.w += a0.w*wR.x + a1.w*wR.y + a2.w*wR.z + a3.w*wR.w;
            }
            float4* R4 = (float4*)red;
            R4[((8 + wv) * 12 + 0 + u) * 16 + bp] = c0;
            R4[((8 + wv) * 12 + 4 + u) * 16 + bp] = c1;
            R4[((8 + wv) * 12 + 8 + u) * 16 + bp] = c2;
            float4* RB4 = (float4*)redB;
            RB4[(wv * 4 + u) * 16 + bp] = cR;
        }
        __syncthreads();

        float xh = 0.f;
        if (have) {
            xh = brol[dl];
            #pragma unroll
            for (int g = 0; g < 8; ++g)
                xh += redB[(g * 4 + dl) * 64 + b];
            if (t < SS - 1) {
                float xi = (mv_pf > 0.5f) ? xv_pf : xh;
                ast4(&buf[(size_t)(sbase + d0 + dl) * 64 + b], xi);        // sc1
                ast4(&buf[(size_t)(sbase + 207 + d0 + dl) * 64 + b], mv_pf);
            }
        }
        if (t == SS - 1) {
            if (have) stage[(t * DD + d0 + dl) * 64 + b] = xh;
            break;
        }

        // ---- arrive 1: xin_t published (drain = 2 ast4 only) ----
        ++gen;
        asm volatile("s_waitcnt vmcnt(0)" ::: "memory");
        __syncthreads();
        if (tid == 0)
            __hip_atomic_store(&flags[wg * 32], gen, __ATOMIC_RELAXED, AG);

        // deferred output store (out of the drain set)
        if (have) stage[(t * DD + d0 + dl) * 64 + b] = xh;

        // ---- wait 1 ----
        if (tid < 64) {
            unsigned* f = &flags[tid * 32];
            while (__hip_atomic_load(f, __ATOMIC_RELAXED, AG) < gen) {}
        }
        __syncthreads();

        // ---- gate xin GEMV: 8 waves x 52 rows (virgin cached reads) ----
        run_rangeX(A4, wgl, red, u, bp, wv * 52, sbase + wv * 52, 52, wv);
        __syncthreads();

        // ---- combine + gates + publish h_{t+1} into slot t+1 (sc1) ----
        if (tid < 256) {
            const int u2 = tid >> 6, b2 = tid & 63;
            float gir = bihl[0 + u2], giz = bihl[4 + u2], gin = bihl[8 + u2];
            float ghr = bhhl[0 + u2], ghz = bhhl[4 + u2], ghn = bhhl[8 + u2];
            #pragma unroll
            for (int s = 0; s < 8; ++s) {
                gir += red[(s * 12 + 0 + u2) * 64 + b2];
                giz += red[(s * 12 + 4 + u2) * 64 + b2];
                gin += red[(s * 12 + 8 + u2) * 64 + b2];
                ghr += red[((8 + s) * 12 + 0 + u2) * 64 + b2];
                ghz += red[((8 + s) * 12 + 4 + u2) * 64 + b2];
                ghn += red[((8 + s) * 12 + 8 + u2) * 64 + b2];
            }
            float r = 1.f / (1.f + __expf(-(gir + ghr)));
            float z = 1.f / (1.f + __expf(-(giz + ghz)));
            float n = tanhf(gin + r * ghn);
            float hn = (1.f - z) * n + z * hloc[u2 * 64 + b2];
            hloc[u2 * 64 + b2] = hn;
            ast4(&buf[(size_t)((t + 1) * SROWS + HOFF + wg * 4 + u2) * 64 + b2], hn);
        }

        // ---- arrive 2: h_{t+1} published ----
        ++gen;
        asm volatile("s_waitcnt vmcnt(0)" ::: "memory");
        __syncthreads();
        if (tid == 0)
            __hip_atomic_store(&flags[wg * 32], gen, __ATOMIC_RELAXED, AG);

        // ---- overlap: next x/mask prefetch ----
        if (have && t + 1 < SS - 1) {
            xv_pf = x[gbase + (size_t)(t + 1) * DD];
            mv_pf = mask[gbase + (size_t)(t + 1) * DD];
        }

        // ---- wait 2 ----
        if (tid < 64) {
            unsigned* f = &flags[tid * 32];
            while (__hip_atomic_load(f, __ATOMIC_RELAXED, AG) < gen) {}
        }
        __syncthreads();
    }
}

// epilogue: stage[t][d][b] -> out[b][t][d]
__global__ __launch_bounds__(256) void out_transpose(
    const float* __restrict__ stage, float* __restrict__ out)
{
    __shared__ float lds[DD * 65];
    const int t = blockIdx.x;
    const float* st = stage + (size_t)t * DD * 64;
    for (int i = threadIdx.x; i < DD * 64; i += 256) {
        int d = i >> 6, b = i & 63;
        lds[d * 65 + b] = st[i];
    }
    __syncthreads();
    for (int i = threadIdx.x; i < DD * 64; i += 256) {
        int b = i / DD, d = i - b * DD;
        out[(size_t)b * (SS * DD) + (size_t)t * DD + d] = lds[d * 65 + b];
    }
}

// ================= v3 middle fallback (round-3 proven, 8.1 ms) =================
__device__ __forceinline__ void v3_gbar(unsigned* flags, int wg, unsigned g) {
    __syncthreads();
    if (threadIdx.x < 64) {
        if (threadIdx.x == 0) {
            __builtin_amdgcn_fence(__ATOMIC_RELEASE, "agent");
            __hip_atomic_store(&flags[wg * 32], g, __ATOMIC_RELAXED, AG);
        }
        unsigned* f = &flags[threadIdx.x * 32];
        while (__hip_atomic_load(f, __ATOMIC_RELAXED, AG) < g) { }
        __builtin_amdgcn_fence(__ATOMIC_ACQUIRE, "agent");
    }
    __syncthreads();
}

__global__ __launch_bounds__(256) void v3_init(float* __restrict__ ws) {
    int i = blockIdx.x * blockDim.x + threadIdx.x;
    const int nz = (672 - 414) * 64;
    for (int idx = i; idx < nz; idx += gridDim.x * blockDim.x)
        ws[414 * 64 + idx] = 0.f;
    for (int idx = i; idx < V3_FLAGS; idx += gridDim.x * blockDim.x)
        ((unsigned*)(ws + V3_ACT))[idx] = 0u;
}

template<bool STAGE>
__global__ __launch_bounds__(256) void v3_persist(
    const float* __restrict__ x, const float* __restrict__ mask,
    const float* __restrict__ W_ih, const float* __restrict__ W_hh,
    const float* __restrict__ b_ih, const float* __restrict__ b_hh,
    const float* __restrict__ W_ro, const float* __restrict__ b_ro,
    float* __restrict__ ws, float* __restrict__ out)
{
    const int wg = blockIdx.x;
    const int tid = threadIdx.x;
    const int lane = tid & 63;
    const int wv = tid >> 6;

    float* actg = ws;
    unsigned* flags = (unsigned*)(ws + V3_ACT);
    float* stage = ws + V3_ACT + V3_FLAGS;

    __shared__ float wgl[12 * LDW];
    __shared__ float wrol[4 * 256];
    __shared__ float red[5 * 12 * 64];
    __shared__ float redB[16 * 64];
    __shared__ float hloc[4 * 64];
    __shared__ float bihl[12], bhhl[12], brol[4];

    const int d0 = (207 * wg) / NWG;
    const int d1 = (207 * (wg + 1)) / NWG;
    const int dc = d1 - d0;

    for (int i = tid; i < 12 * LDW; i += 256) {
        int r = i / LDW, c = i - r * LDW;
        int rg = (r >> 2) * 256 + wg * 4 + (r & 3);
        float v = 0.f;
        if (c < 414) v = W_ih[rg * 414 + c];
        else if (c >= 416 && c < 672) v = W_hh[rg * 256 + (c - 416)];
        wgl[i] = v;
    }
    for (int i = tid; i < 4 * 256; i += 256) {
        int dl_ = i >> 8, j = i & 255;
        wrol[i] = (dl_ < dc) ? W_ro[(d0 + dl_) * 256 + j] : 0.f;
    }
    if (tid < 12) {
        int rg = (tid >> 2) * 256 + wg * 4 + (tid & 3);
        bihl[tid] = b_ih[rg];
        bhhl[tid] = b_hh[rg];
    }
    if (tid < 4) brol[tid] = (tid < dc) ? b_ro[d0 + tid] : 0.f;
    hloc[tid] = 0.f;
    __syncthreads();

    const float4* A4 = (const float4*)actg;
    const int u = lane >> 4;
    const int bp = lane & 15;

    const bool have = (tid < dc * 64);
    const int dl = tid >> 6, b = tid & 63;
    const size_t gbase = (size_t)b * (SS * DD) + (d0 + dl);
    float xv_pf = 0.f, mv_pf = 0.f;
    if (have) { xv_pf = x[gbase]; mv_pf = mask[gbase]; }

    unsigned gen = 0;

    for (int t = 0; t < SS; ++t) {
        const int par = t & 1;
        const int hrow0 = V3_HBASE + par * 256;

        {
            const float* hrow = actg + hrow0 * 64;
            const int jb = wv * 64;
            float acc0 = 0.f, acc1 = 0.f, acc2 = 0.f, acc3 = 0.f;
            #pragma unroll 4
            for (int j = 0; j < 64; j += 4) {
                float a0 = hrow[(jb + j + 0) * 64 + lane];
                float a1 = hrow[(jb + j + 1) * 64 + lane];
                float a2 = hrow[(jb + j + 2) * 64 + lane];
                float a3 = hrow[(jb + j + 3) * 64 + lane];
                float4 w0 = *(const float4*)&wrol[0 * 256 + jb + j];
                float4 w1 = *(const float4*)&wrol[1 * 256 + jb + j];
                float4 w2 = *(const float4*)&wrol[2 * 256 + jb + j];
                float4 w3 = *(const float4*)&wrol[3 * 256 + jb + j];
                acc0 += a0*w0.x + a1*w0.y + a2*w0.z + a3*w0.w;
                acc1 += a0*w1.x + a1*w1.y + a2*w1.z + a3*w1.w;
                acc2 += a0*w2.x + a1*w2.y + a2*w2.z + a3*w2.w;
                acc3 += a0*w3.x + a1*w3.y + a2*w3.z + a3*w3.w;
            }
            redB[(wv * 4 + 0) * 64 + lane] = acc0;
            redB[(wv * 4 + 1) * 64 + lane] = acc1;
            redB[(wv * 4 + 2) * 64 + lane] = acc2;
            redB[(wv * 4 + 3) * 64 + lane] = acc3;
        }
        __syncthreads();
        if (have) {
            float xh = redB[(0 * 4 + dl) * 64 + b] + redB[(1 * 4 + dl) * 64 + b]
                     + redB[(2 * 4 + dl) * 64 + b] + redB[(3 * 4 + dl) * 64 + b]
                     + brol[dl];
            if (STAGE) stage[(t * DD + d0 + dl) * 64 + b] = xh;
            else       out[gbase + (size_t)t * DD] = xh;
            if (t < SS - 1) {
                float xi = (mv_pf > 0.5f) ? xv_pf : xh;
                actg[(d0 + dl) * 64 + b] = xi;
                actg[(207 + d0 + dl) * 64 + b] = mv_pf;
            }
        }
        if (t == SS - 1) break;

        if (have && t + 1 < SS - 1) {
            xv_pf = x[gbase + (size_t)(t + 1) * DD];
            mv_pf = mask[gbase + (size_t)(t + 1) * DD];
        }

        v3_gbar(flags, wg, ++gen);

        if (wv == 0)      run_range6(A4, wgl, red, u, bp, 0,   0,          168, 0);
        else if (wv == 1) run_range6(A4, wgl, red, u, bp, 168, 168,        168, 1);
        else if (wv == 2) {
            run_range6(A4, wgl, red, u, bp, 336, 336,        80,  2);
            run_range6(A4, wgl, red, u, bp, 416, hrow0,      96,  3);
        } else            run_range6(A4, wgl, red, u, bp, 512, hrow0 + 96, 160, 4);
        __syncthreads();
        {
            const int u2 = tid >> 6, b2 = tid & 63;
            float gir = red[(0*12 + 0 + u2)*64 + b2] + red[(1*12 + 0 + u2)*64 + b2]
                      + red[(2*12 + 0 + u2)*64 + b2] + bihl[0 + u2];
            float giz = red[(0*12 + 4 + u2)*64 + b2] + red[(1*12 + 4 + u2)*64 + b2]
                      + red[(2*12 + 4 + u2)*64 + b2] + bihl[4 + u2];
            float gin = red[(0*12 + 8 + u2)*64 + b2] + red[(1*12 + 8 + u2)*64 + b2]
                      + red[(2*12 + 8 + u2)*64 + b2] + bihl[8 + u2];
            float ghr = red[(3*12 + 0 + u2)*64 + b2] + red[(4*12 + 0 + u2)*64 + b2] + bhhl[0 + u2];
            float ghz = red[(3*12 + 4 + u2)*64 + b2] + red[(4*12 + 4 + u2)*64 + b2] + bhhl[4 + u2];
            float ghn = red[(3*12 + 8 + u2)*64 + b2] + red[(4*12 + 8 + u2)*64 + b2] + bhhl[8 + u2];
            float r = 1.f / (1.f + __expf(-(gir + ghr)));
            float z = 1.f / (1.f + __expf(-(giz + ghz)));
            float n = tanhf(gin + r * ghn);
            float hn = (1.f - z) * n + z * hloc[u2 * 64 + b2];
            hloc[u2 * 64 + b2] = hn;
            actg[(V3_HBASE + (par ^ 1) * 256 + wg * 4 + u2) * 64 + b2] = hn;
        }
        v3_gbar(flags, wg, ++gen);
    }
}

// ---- minimal fallback (one WG per batch) ----
__global__ __launch_bounds__(768) void rnn_fallback(
    const float* __restrict__ x, const float* __restrict__ mask,
    const float* __restrict__ W_ih, const float* __restrict__ W_hh,
    const float* __restrict__ b_ih, const float* __restrict__ b_hh,
    const float* __restrict__ W_ro, const float* __restrict__ b_ro,
    float* __restrict__ out)
{
    const int b = blockIdx.x, tid = threadIdx.x;
    __shared__ float h[HH];
    __shared__ float hnew[HH];
    __shared__ float xin[414 + 2];
    __shared__ float gi[768];
    __shared__ float gh[768];
    __shared__ float xhat[DD];
    const float bih = b_ih[tid], bhh = b_hh[tid];
    const float bro = (tid < DD) ? b_ro[tid] : 0.f;
    if (tid < HH) h[tid] = 0.f;
    if (tid < DD) xhat[tid] = bro;
    __syncthreads();
    const float* xb = x + (size_t)b * SS * DD;
    const float* mb = mask + (size_t)b * SS * DD;
    float* ob = out + (size_t)b * SS * DD;
    for (int t = 0; t < SS; ++t) {
        if (tid < DD) ob[t * DD + tid] = xhat[tid];
        if (t == SS - 1) break;
        if (tid < DD) {
            float m = mb[t * DD + tid], xv = xb[t * DD + tid];
            xin[tid] = (m > 0.5f) ? xv : xhat[tid];
            xin[DD + tid] = m;
        }
        __syncthreads();
        float accI = bih, accH = bhh;
        const float* wi = W_ih + (size_t)tid * 414;
        for (int k = 0; k < 414; ++k) accI += wi[k] * xin[k];
        const float* wh = W_hh + (size_t)tid * HH;
        for (int k = 0; k < HH; ++k) accH += wh[k] * h[k];
        gi[tid] = accI; gh[tid] = accH;
        __syncthreads();
        if (tid < HH) {
            float r = 1.f / (1.f + __expf(-(gi[tid] + gh[tid])));
            float z = 1.f / (1.f + __expf(-(gi[HH + tid] + gh[HH + tid])));
            float n = tanhf(gi[2 * HH + tid] + r * gh[2 * HH + tid]);
            hnew[tid] = (1.f - z) * n + z * h[tid];
        }
        __syncthreads();
        if (tid < DD) {
            float acc = bro;
            const float* wr = W_ro + (size_t)tid * HH;
            for (int k = 0; k < HH; ++k) acc += wr[k] * hnew[k];
            xhat[tid] = acc;
        }
        if (tid < HH) h[tid] = hnew[tid];
        __syncthreads();
    }
}

extern "C" void kernel_launch(void* const* d_in, const int* in_sizes, int n_in,
                              void* d_out, int out_size, void* d_ws, size_t ws_size,
                              hipStream_t stream) {
    const float* x    = (const float*)d_in[0];
    const float* mask = (const float*)d_in[1];
    const float* W_ih = (const float*)d_in[2];
    const float* W_hh = (const float*)d_in[3];
    const float* b_ih = (const float*)d_in[4];
    const float* b_hh = (const float*)d_in[5];
    const float* W_ro = (const float*)d_in[6];
    const float* b_ro = (const float*)d_in[7];
    float* out = (float*)d_out;
    float* ws  = (float*)d_ws;

    if (ws_size >= WS_NEED6) {
        hipLaunchKernelGGL(rnn_init6, dim3(64), dim3(256), 0, stream, ws);
        hipLaunchKernelGGL(rnn_persist14, dim3(NWG), dim3(512), 0, stream,
                           x, mask, W_ih, W_hh, b_ih, b_hh, W_ro, b_ro, ws, out);
        hipLaunchKernelGGL(out_transpose, dim3(SS), dim3(256), 0, stream,
                           ws + BUF_FLOATS + FLAG_U32, out);
    } else if (ws_size >= V3_WS_FULL) {
        hipLaunchKernelGGL(v3_init, dim3(32), dim3(256), 0, stream, ws);
        hipLaunchKernelGGL((v3_persist<true>), dim3(NWG), dim3(256), 0, stream,
                           x, mask, W_ih, W_hh, b_ih, b_hh, W_ro, b_ro, ws, out);
        hipLaunchKernelGGL(out_transpose, dim3(SS), dim3(256), 0, stream,
                           ws + V3_ACT + V3_FLAGS, out);
    } else if (ws_size >= V3_WS_SMALL) {
        hipLaunchKernelGGL(v3_init, dim3(32), dim3(256), 0, stream, ws);
        hipLaunchKernelGGL((v3_persist<false>), dim3(NWG), dim3(256), 0, stream,
                           x, mask, W_ih, W_hh, b_ih, b_hh, W_ro, b_ro, ws, out);
    } else {
        hipLaunchKernelGGL(rnn_fallback, dim3(BB), dim3(768), 0, stream,
                           x, mask, W_ih, W_hh, b_ih, b_hh, W_ro, b_ro, out);
    }
}

// Round 10
// 5003.498 us; speedup vs baseline: 1.0195x; 1.0195x over previous
//
#include <hip/hip_runtime.h>
#include <math.h>

#define BB 64
#define SS 512
#define DD 207
#define HH 256
#define NWG 64
#define LDW 676   // wgl row stride (%32==4 -> staggered banks)
#define ROW 260   // wrol row stride
#define AG __HIP_MEMORY_SCOPE_AGENT

// ================= v15r: resubmission of v15 (R9 bench was infra-failed) =====
// 64 WGs x 512 threads, v13's fused PhaseB+gh pass, identical publishes/flags.
// Change vs v13: each wave waits ONLY on its true producers:
//   - fused h-pass of wave wv reads h-units 32wv..32wv+31 -> 8 producer WGs
//     (wait at loop top, before the fused pass).
//   - xin pass of wave wv reads a contiguous d-interval -> ~17 producer WGs
//     (wave 3 additionally needs WG 0: row 207 = mask d0). Conservative WG
//     interval [64*dlo/207, 64*dhi/207 + 1] provably covers owners.
// tid<64 wait blocks + their __syncthreads() removed; waves spin per-lane
// (divergent, reconverging). Cross-wave red/redB hazards remain fenced by the
// arr1/arr2 __syncthreads(). Flags monotone: arr1(t)=2t+1, arr2(t)=2t+2,
// h[t] wait target 2t. Dependency graph acyclic -> deadlock-free.
#define SROWS 672
#define HOFF  416
#define SLOT  (SROWS * 64)
#define BUF_FLOATS ((size_t)SS * SLOT)
#define FLAG_U32 (64 * 32)
#define STAGE_FLOATS ((size_t)SS * DD * 64)
#define WS_NEED6 ((BUF_FLOATS + FLAG_U32 + STAGE_FLOATS) * sizeof(float))

// ---- v3 fallback layout (round-3 proven path) ----
#define V3_AROWS 928
#define V3_HBASE 416
#define V3_ACT (V3_AROWS * 64)
#define V3_FLAGS (64 * 32)
#define V3_WS_SMALL ((size_t)(V3_ACT + V3_FLAGS) * sizeof(float))
#define V3_WS_FULL  ((size_t)(V3_ACT + V3_FLAGS + STAGE_FLOATS) * sizeof(float))

__device__ __forceinline__ void ast4(float* p, float v) {
    union { float f; unsigned u; } c; c.f = v;
    __hip_atomic_store((unsigned*)p, c.u, __ATOMIC_RELAXED, AG);
}

// 12-row (3 gates x unit u) GEMV partial, NORMAL float4 loads (round-3 shape).
// gr0 = global float4-row base (t*672 + local row), wc0 = weight col base.
__device__ __forceinline__ void run_range6(
    const float4* __restrict__ A4, const float* __restrict__ wgl,
    float* __restrict__ red, int u, int bp, int wc0, int gr0, int len, int slot)
{
    float4 c0 = make_float4(0.f, 0.f, 0.f, 0.f);
    float4 c1 = c0, c2 = c0;
    #pragma unroll 4
    for (int k = 0; k < len; k += 4) {
        float4 a0 = A4[(gr0 + k + 0) * 16 + bp];
        float4 a1 = A4[(gr0 + k + 1) * 16 + bp];
        float4 a2 = A4[(gr0 + k + 2) * 16 + bp];
        float4 a3 = A4[(gr0 + k + 3) * 16 + bp];
        float4 w0 = *(const float4*)&wgl[(0 + u) * LDW + wc0 + k];
        float4 w1 = *(const float4*)&wgl[(4 + u) * LDW + wc0 + k];
        float4 w2 = *(const float4*)&wgl[(8 + u) * LDW + wc0 + k];
        c0.x += a0.x*w0.x + a1.x*w0.y + a2.x*w0.z + a3.x*w0.w;
        c0.y += a0.y*w0.x + a1.y*w0.y + a2.y*w0.z + a3.y*w0.w;
        c0.z += a0.z*w0.x + a1.z*w0.y + a2.z*w0.z + a3.z*w0.w;
        c0.w += a0.w*w0.x + a1.w*w0.y + a2.w*w0.z + a3.w*w0.w;
        c1.x += a0.x*w1.x + a1.x*w1.y + a2.x*w1.z + a3.x*w1.w;
        c1.y += a0.y*w1.x + a1.y*w1.y + a2.y*w1.z + a3.y*w1.w;
        c1.z += a0.z*w1.x + a1.z*w1.y + a2.z*w1.z + a3.z*w1.w;
        c1.w += a0.w*w1.x + a1.w*w1.y + a2.w*w1.z + a3.w*w1.w;
        c2.x += a0.x*w2.x + a1.x*w2.y + a2.x*w2.z + a3.x*w2.w;
        c2.y += a0.y*w2.x + a1.y*w2.y + a2.y*w2.z + a3.y*w2.w;
        c2.z += a0.z*w2.x + a1.z*w2.y + a2.z*w2.z + a3.z*w2.w;
        c2.w += a0.w*w2.x + a1.w*w2.y + a2.w*w2.z + a3.w*w2.w;
    }
    float4* R4 = (float4*)red;
    R4[(slot * 12 + 0 + u) * 16 + bp] = c0;
    R4[(slot * 12 + 4 + u) * 16 + bp] = c1;
    R4[(slot * 12 + 8 + u) * 16 + bp] = c2;
}

__global__ __launch_bounds__(256) void rnn_init6(float* __restrict__ ws) {
    int i = blockIdx.x * blockDim.x + threadIdx.x;
    // zero slot-0 h rows (h_0 = 0)
    for (int idx = i; idx < HH * 64; idx += gridDim.x * blockDim.x)
        ws[HOFF * 64 + idx] = 0.f;
    unsigned* fl = (unsigned*)(ws + BUF_FLOATS);
    for (int idx = i; idx < FLAG_U32; idx += gridDim.x * blockDim.x)
        fl[idx] = 0u;
}

__global__ __launch_bounds__(512) void rnn_persist15(
    const float* __restrict__ x, const float* __restrict__ mask,
    const float* __restrict__ W_ih, const float* __restrict__ W_hh,
    const float* __restrict__ b_ih, const float* __restrict__ b_hh,
    const float* __restrict__ W_ro, const float* __restrict__ b_ro,
    float* __restrict__ ws, float* __restrict__ out)
{
    const int wg = blockIdx.x;
    const int tid = threadIdx.x;
    const int lane = tid & 63;
    const int wv = tid >> 6;          // 0..7

    float* buf = ws;
    unsigned* flags = (unsigned*)(ws + BUF_FLOATS);
    float* stage = ws + BUF_FLOATS + FLAG_U32;

    __shared__ float wgl[12 * LDW];      // 12 gate rows x 676 (cols 414/415 = 0)
    __shared__ float wrol[4 * ROW];      // up to 4 readout rows
    __shared__ float red[16 * 12 * 64];  // slots 0-7 xin partials, 8-15 gh
    __shared__ float redB[32 * 64];      // readout partials (8 waves x 4 rows)
    __shared__ float hloc[4 * 64];       // own hidden units
    __shared__ float bihl[12], bhhl[12], brol[4];

    const int d0 = (207 * wg) / NWG;
    const int d1 = (207 * (wg + 1)) / NWG;
    const int dc = d1 - d0;

    for (int i = tid; i < 12 * LDW; i += 512) {
        int r = i / LDW, c = i - r * LDW;
        int rg = (r >> 2) * 256 + wg * 4 + (r & 3);
        float v = 0.f;
        if (c < 414) v = W_ih[rg * 414 + c];
        else if (c >= 416 && c < 672) v = W_hh[rg * 256 + (c - 416)];
        wgl[i] = v;
    }
    for (int i = tid; i < 4 * 256; i += 512) {
        int dl_ = i >> 8, j = i & 255;
        wrol[dl_ * ROW + j] = (dl_ < dc) ? W_ro[(d0 + dl_) * 256 + j] : 0.f;
    }
    if (tid < 12) {
        int rg = (tid >> 2) * 256 + wg * 4 + (tid & 3);
        bihl[tid] = b_ih[rg];
        bhhl[tid] = b_hh[rg];
    }
    if (tid < 4) brol[tid] = (tid < dc) ? b_ro[d0 + tid] : 0.f;
    if (tid < 256) hloc[tid] = 0.f;
    __syncthreads();

    const float4* A4 = (const float4*)buf;
    const int u  = lane >> 4;
    const int bp = lane & 15;

    const bool have = (tid < dc * 64);
    const int dl = tid >> 6, b = tid & 63;
    const size_t gbase = (size_t)b * (SS * DD) + (d0 + dl);
    float xv_pf = 0.f, mv_pf = 0.f;
    if (have) { xv_pf = x[gbase]; mv_pf = mask[gbase]; }

    // ---- per-wave producer sets ----
    // xin pass of wave wv reads rows [wv*52, wv*52+52): x-rows -> d = row,
    // mask-rows -> d = row-207. d-intervals per wave (wave 3 row 207 = mask
    // d0 -> extra producer WG 0):
    int dlo, dhi; bool extra0 = false;
    switch (wv) {
        case 0: dlo = 0;   dhi = 51;  break;
        case 1: dlo = 52;  dhi = 103; break;
        case 2: dlo = 104; dhi = 155; break;
        case 3: dlo = 156; dhi = 206; extra0 = true; break;
        case 4: dlo = 1;   dhi = 52;  break;
        case 5: dlo = 53;  dhi = 104; break;
        case 6: dlo = 105; dhi = 156; break;
        default: dlo = 157; dhi = 206; break;
    }
    const int xw_lo = (64 * dlo) / 207;
    int xw_hi = (64 * dhi) / 207 + 1;
    if (xw_hi > 63) xw_hi = 63;
    const int xcnt = xw_hi - xw_lo + 1;
    // flag index this lane polls for the xin wait (or -1)
    int xw = -1;
    if (lane < xcnt) xw = xw_lo + lane;
    else if (extra0 && lane == xcnt) xw = 0;
    // h wait: fused pass of wave wv reads h-units 32wv..32wv+31 -> WGs
    // 8wv..8wv+7. Lane l<8 polls WG 8wv+l.
    const int hw = (lane < 8) ? (8 * wv + lane) : -1;

    for (int t = 0; t < SS; ++t) {
        const int sbase = t * SROWS;        // this step's slot (row units)
        const unsigned gH = 2u * t;         // h[t] published with this value
        const unsigned g1 = 2u * t + 1;     // xin_t flag
        const unsigned g2 = 2u * t + 2;     // h[t+1] flag

        // ---- per-wave wait: h[t] from this wave's 8 producers ----
        if (t > 0 && hw >= 0) {
            unsigned* f = &flags[hw * 32];
            while (__hip_atomic_load(f, __ATOMIC_RELAXED, AG) < gH) {}
        }

        // ---- Fused Phase B + gh: ONE pass over h_t (float4, virgin reads) ----
        {
            const int jb = wv * 32;
            const int gr0 = sbase + HOFF + jb;     // h rows (float4 rows)
            const int wc0 = 416 + jb;              // gate weight cols
            float4 c0 = make_float4(0.f, 0.f, 0.f, 0.f);
            float4 c1 = c0, c2 = c0, cR = c0;
            #pragma unroll 4
            for (int k = 0; k < 32; k += 4) {
                float4 a0 = A4[(gr0 + k + 0) * 16 + bp];
                float4 a1 = A4[(gr0 + k + 1) * 16 + bp];
                float4 a2 = A4[(gr0 + k + 2) * 16 + bp];
                float4 a3 = A4[(gr0 + k + 3) * 16 + bp];
                float4 w0 = *(const float4*)&wgl[(0 + u) * LDW + wc0 + k];
                float4 w1 = *(const float4*)&wgl[(4 + u) * LDW + wc0 + k];
                float4 w2 = *(const float4*)&wgl[(8 + u) * LDW + wc0 + k];
                float4 wR = *(const float4*)&wrol[u * ROW + jb + k];
                c0.x += a0.x*w0.x + a1.x*w0.y + a2.x*w0.z + a3.x*w0.w;
                c0.y += a0.y*w0.x + a1.y*w0.y + a2.y*w0.z + a3.y*w0.w;
                c0.z += a0.z*w0.x + a1.z*w0.z + a2.z*w0.z + a3.z*w0.w;
                c0.w += a0.w*w0.x + a1.w*w0.y + a2.w*w0.z + a3.w*w0.w;
                c1.x += a0.x*w1.x + a1.x*w1.y + a2.x*w1.z + a3.x*w1.w;
                c1.y += a0.y*w1.x + a1.y*w1.y + a2.y*w1.z + a3.y*w1.w;
                c1.z += a0.z*w1.x + a1.z*w1.y + a2.z*w1.z + a3.z*w1.w;
                c1.w += a0.w*w1.x + a1.w*w1.y + a2.w*w1.z + a3.w*w1.w;
                c2.x += a0.x*w2.x + a1.x*w2.y + a2.x*w2.z + a3.x*w2.w;
                c2.y += a0.y*w2.x + a1.y*w2.y + a2.y*w2.z + a3.y*w2.w;
                c2.z += a0.z*w2.x + a1.z*w2.y + a2.z*w2.z + a3.z*w2.w;
                c2.w += a0.w*w2.x + a1.w*w2.y + a2.w*w2.z + a3.w*w2.w;
                cR.x += a0.x*wR.x + a1.x*wR.y + a2.x*wR.z + a3.x*wR.w;
                cR.y += a0.y*wR.x + a1.y*wR.y + a2.y*wR.z + a3.y*wR.w;
                cR.z += a0.z*wR.x + a1.z*wR.y + a2.z*wR.z + a3.z*wR.w;
                cR.w += a0.w*wR.x + a1.w*wR.y + a2.w*wR.z + a3.w*wR.w;
            }
            float4* R4 = (float4*)red;
            R4[((8 + wv) * 12 + 0 + u) * 16 + bp] = c0;
            R4[((8 + wv) * 12 + 4 + u) * 16 + bp] = c1;
            R4[((8 + wv) * 12 + 8 + u) * 16 + bp] = c2;
            float4* RB4 = (float4*)redB;
            RB4[(wv * 4 + u) * 16 + bp] = cR;
        }
        __syncthreads();

        float xh = 0.f;
        if (have) {
            xh = brol[dl];
            #pragma unroll
            for (int g = 0; g < 8; ++g)
                xh += redB[(g * 4 + dl) * 64 + b];
            if (t < SS - 1) {
                float xi = (mv_pf > 0.5f) ? xv_pf : xh;
                ast4(&buf[(size_t)(sbase + d0 + dl) * 64 + b], xi);        // sc1
                ast4(&buf[(size_t)(sbase + 207 + d0 + dl) * 64 + b], mv_pf);
            }
        }
        if (t == SS - 1) {
            if (have) stage[(t * DD + d0 + dl) * 64 + b] = xh;
            break;
        }

        // ---- arrive 1: xin_t published (drain = 2 ast4 only) ----
        asm volatile("s_waitcnt vmcnt(0)" ::: "memory");
        __syncthreads();
        if (tid == 0)
            __hip_atomic_store(&flags[wg * 32], g1, __ATOMIC_RELAXED, AG);

        // deferred output store (out of the drain set)
        if (have) stage[(t * DD + d0 + dl) * 64 + b] = xh;

        // ---- per-wave wait: xin rows from this wave's ~17 producers ----
        if (xw >= 0) {
            unsigned* f = &flags[xw * 32];
            while (__hip_atomic_load(f, __ATOMIC_RELAXED, AG) < g1) {}
        }

        // ---- gate xin GEMV: 8 waves x 52 rows (virgin cached reads) ----
        run_range6(A4, wgl, red, u, bp, wv * 52, sbase + wv * 52, 52, wv);
        __syncthreads();

        // ---- combine + gates + publish h_{t+1} into slot t+1 (sc1) ----
        if (tid < 256) {
            const int u2 = tid >> 6, b2 = tid & 63;
            float gir = bihl[0 + u2], giz = bihl[4 + u2], gin = bihl[8 + u2];
            float ghr = bhhl[0 + u2], ghz = bhhl[4 + u2], ghn = bhhl[8 + u2];
            #pragma unroll
            for (int s = 0; s < 8; ++s) {
                gir += red[(s * 12 + 0 + u2) * 64 + b2];
                giz += red[(s * 12 + 4 + u2) * 64 + b2];
                gin += red[(s * 12 + 8 + u2) * 64 + b2];
                ghr += red[((8 + s) * 12 + 0 + u2) * 64 + b2];
                ghz += red[((8 + s) * 12 + 4 + u2) * 64 + b2];
                ghn += red[((8 + s) * 12 + 8 + u2) * 64 + b2];
            }
            float r = 1.f / (1.f + __expf(-(gir + ghr)));
            float z = 1.f / (1.f + __expf(-(giz + ghz)));
            float n = tanhf(gin + r * ghn);
            float hn = (1.f - z) * n + z * hloc[u2 * 64 + b2];
            hloc[u2 * 64 + b2] = hn;
            ast4(&buf[(size_t)((t + 1) * SROWS + HOFF + wg * 4 + u2) * 64 + b2], hn);
        }

        // ---- arrive 2: h_{t+1} published ----
        asm volatile("s_waitcnt vmcnt(0)" ::: "memory");
        __syncthreads();
        if (tid == 0)
            __hip_atomic_store(&flags[wg * 32], g2, __ATOMIC_RELAXED, AG);

        // ---- overlap: next x/mask prefetch (h-wait happens at loop top) ----
        if (have && t + 1 < SS - 1) {
            xv_pf = x[gbase + (size_t)(t + 1) * DD];
            mv_pf = mask[gbase + (size_t)(t + 1) * DD];
        }
    }
}

// epilogue: stage[t][d][b] -> out[b][t][d]
__global__ __launch_bounds__(256) void out_transpose(
    const float* __restrict__ stage, float* __restrict__ out)
{
    __shared__ float lds[DD * 65];
    const int t = blockIdx.x;
    const float* st = stage + (size_t)t * DD * 64;
    for (int i = threadIdx.x; i < DD * 64; i += 256) {
        int d = i >> 6, b = i & 63;
        lds[d * 65 + b] = st[i];
    }
    __syncthreads();
    for (int i = threadIdx.x; i < DD * 64; i += 256) {
        int b = i / DD, d = i - b * DD;
        out[(size_t)b * (SS * DD) + (size_t)t * DD + d] = lds[d * 65 + b];
    }
}

// ================= v3 middle fallback (round-3 proven, 8.1 ms) =================
__device__ __forceinline__ void v3_gbar(unsigned* flags, int wg, unsigned g) {
    __syncthreads();
    if (threadIdx.x < 64) {
        if (threadIdx.x == 0) {
            __builtin_amdgcn_fence(__ATOMIC_RELEASE, "agent");
            __hip_atomic_store(&flags[wg * 32], g, __ATOMIC_RELAXED, AG);
        }
        unsigned* f = &flags[threadIdx.x * 32];
        while (__hip_atomic_load(f, __ATOMIC_RELAXED, AG) < g) { }
        __builtin_amdgcn_fence(__ATOMIC_ACQUIRE, "agent");
    }
    __syncthreads();
}

__global__ __launch_bounds__(256) void v3_init(float* __restrict__ ws) {
    int i = blockIdx.x * blockDim.x + threadIdx.x;
    const int nz = (672 - 414) * 64;
    for (int idx = i; idx < nz; idx += gridDim.x * blockDim.x)
        ws[414 * 64 + idx] = 0.f;
    for (int idx = i; idx < V3_FLAGS; idx += gridDim.x * blockDim.x)
        ((unsigned*)(ws + V3_ACT))[idx] = 0u;
}

template<bool STAGE>
__global__ __launch_bounds__(256) void v3_persist(
    const float* __restrict__ x, const float* __restrict__ mask,
    const float* __restrict__ W_ih, const float* __restrict__ W_hh,
    const float* __restrict__ b_ih, const float* __restrict__ b_hh,
    const float* __restrict__ W_ro, const float* __restrict__ b_ro,
    float* __restrict__ ws, float* __restrict__ out)
{
    const int wg = blockIdx.x;
    const int tid = threadIdx.x;
    const int lane = tid & 63;
    const int wv = tid >> 6;

    float* actg = ws;
    unsigned* flags = (unsigned*)(ws + V3_ACT);
    float* stage = ws + V3_ACT + V3_FLAGS;

    __shared__ float wgl[12 * LDW];
    __shared__ float wrol[4 * 256];
    __shared__ float red[5 * 12 * 64];
    __shared__ float redB[16 * 64];
    __shared__ float hloc[4 * 64];
    __shared__ float bihl[12], bhhl[12], brol[4];

    const int d0 = (207 * wg) / NWG;
    const int d1 = (207 * (wg + 1)) / NWG;
    const int dc = d1 - d0;

    for (int i = tid; i < 12 * LDW; i += 256) {
        int r = i / LDW, c = i - r * LDW;
        int rg = (r >> 2) * 256 + wg * 4 + (r & 3);
        float v = 0.f;
        if (c < 414) v = W_ih[rg * 414 + c];
        else if (c >= 416 && c < 672) v = W_hh[rg * 256 + (c - 416)];
        wgl[i] = v;
    }
    for (int i = tid; i < 4 * 256; i += 256) {
        int dl_ = i >> 8, j = i & 255;
        wrol[i] = (dl_ < dc) ? W_ro[(d0 + dl_) * 256 + j] : 0.f;
    }
    if (tid < 12) {
        int rg = (tid >> 2) * 256 + wg * 4 + (tid & 3);
        bihl[tid] = b_ih[rg];
        bhhl[tid] = b_hh[rg];
    }
    if (tid < 4) brol[tid] = (tid < dc) ? b_ro[d0 + tid] : 0.f;
    hloc[tid] = 0.f;
    __syncthreads();

    const float4* A4 = (const float4*)actg;
    const int u = lane >> 4;
    const int bp = lane & 15;

    const bool have = (tid < dc * 64);
    const int dl = tid >> 6, b = tid & 63;
    const size_t gbase = (size_t)b * (SS * DD) + (d0 + dl);
    float xv_pf = 0.f, mv_pf = 0.f;
    if (have) { xv_pf = x[gbase]; mv_pf = mask[gbase]; }

    unsigned gen = 0;

    for (int t = 0; t < SS; ++t) {
        const int par = t & 1;
        const int hrow0 = V3_HBASE + par * 256;

        {
            const float* hrow = actg + hrow0 * 64;
            const int jb = wv * 64;
            float acc0 = 0.f, acc1 = 0.f, acc2 = 0.f, acc3 = 0.f;
            #pragma unroll 4
            for (int j = 0; j < 64; j += 4) {
                float a0 = hrow[(jb + j + 0) * 64 + lane];
                float a1 = hrow[(jb + j + 1) * 64 + lane];
                float a2 = hrow[(jb + j + 2) * 64 + lane];
                float a3 = hrow[(jb + j + 3) * 64 + lane];
                float4 w0 = *(const float4*)&wrol[0 * 256 + jb + j];
                float4 w1 = *(const float4*)&wrol[1 * 256 + jb + j];
                float4 w2 = *(const float4*)&wrol[2 * 256 + jb + j];
                float4 w3 = *(const float4*)&wrol[3 * 256 + jb + j];
                acc0 += a0*w0.x + a1*w0.y + a2*w0.z + a3*w0.w;
                acc1 += a0*w1.x + a1*w1.y + a2*w1.z + a3*w1.w;
                acc2 += a0*w2.x + a1*w2.y + a2*w2.z + a3*w2.w;
                acc3 += a0*w3.x + a1*w3.y + a2*w3.z + a3*w3.w;
            }
            redB[(wv * 4 + 0) * 64 + lane] = acc0;
            redB[(wv * 4 + 1) * 64 + lane] = acc1;
            redB[(wv * 4 + 2) * 64 + lane] = acc2;
            redB[(wv * 4 + 3) * 64 + lane] = acc3;
        }
        __syncthreads();
        if (have) {
            float xh = redB[(0 * 4 + dl) * 64 + b] + redB[(1 * 4 + dl) * 64 + b]
                     + redB[(2 * 4 + dl) * 64 + b] + redB[(3 * 4 + dl) * 64 + b]
                     + brol[dl];
            if (STAGE) stage[(t * DD + d0 + dl) * 64 + b] = xh;
            else       out[gbase + (size_t)t * DD] = xh;
            if (t < SS - 1) {
                float xi = (mv_pf > 0.5f) ? xv_pf : xh;
                actg[(d0 + dl) * 64 + b] = xi;
                actg[(207 + d0 + dl) * 64 + b] = mv_pf;
            }
        }
        if (t == SS - 1) break;

        if (have && t + 1 < SS - 1) {
            xv_pf = x[gbase + (size_t)(t + 1) * DD];
            mv_pf = mask[gbase + (size_t)(t + 1) * DD];
        }

        v3_gbar(flags, wg, ++gen);

        if (wv == 0)      run_range6(A4, wgl, red, u, bp, 0,   0,          168, 0);
        else if (wv == 1) run_range6(A4, wgl, red, u, bp, 168, 168,        168, 1);
        else if (wv == 2) {
            run_range6(A4, wgl, red, u, bp, 336, 336,        80,  2);
            run_range6(A4, wgl, red, u, bp, 416, hrow0,      96,  3);
        } else            run_range6(A4, wgl, red, u, bp, 512, hrow0 + 96, 160, 4);
        __syncthreads();
        {
            const int u2 = tid >> 6, b2 = tid & 63;
            float gir = red[(0*12 + 0 + u2)*64 + b2] + red[(1*12 + 0 + u2)*64 + b2]
                      + red[(2*12 + 0 + u2)*64 + b2] + bihl[0 + u2];
            float giz = red[(0*12 + 4 + u2)*64 + b2] + red[(1*12 + 4 + u2)*64 + b2]
                      + red[(2*12 + 4 + u2)*64 + b2] + bihl[4 + u2];
            float gin = red[(0*12 + 8 + u2)*64 + b2] + red[(1*12 + 8 + u2)*64 + b2]
                      + red[(2*12 + 8 + u2)*64 + b2] + bihl[8 + u2];
            float ghr = red[(3*12 + 0 + u2)*64 + b2] + red[(4*12 + 0 + u2)*64 + b2] + bhhl[0 + u2];
            float ghz = red[(3*12 + 4 + u2)*64 + b2] + red[(4*12 + 4 + u2)*64 + b2] + bhhl[4 + u2];
            float ghn = red[(3*12 + 8 + u2)*64 + b2] + red[(4*12 + 8 + u2)*64 + b2] + bhhl[8 + u2];
            float r = 1.f / (1.f + __expf(-(gir + ghr)));
            float z = 1.f / (1.f + __expf(-(giz + ghz)));
            float n = tanhf(gin + r * ghn);
            float hn = (1.f - z) * n + z * hloc[u2 * 64 + b2];
            hloc[u2 * 64 + b2] = hn;
            actg[(V3_HBASE + (par ^ 1) * 256 + wg * 4 + u2) * 64 + b2] = hn;
        }
        v3_gbar(flags, wg, ++gen);
    }
}

// ---- minimal fallback (one WG per batch) ----
__global__ __launch_bounds__(768) void rnn_fallback(
    const float* __restrict__ x, const float* __restrict__ mask,
    const float* __restrict__ W_ih, const float* __restrict__ W_hh,
    const float* __restrict__ b_ih, const float* __restrict__ b_hh,
    const float* __restrict__ W_ro, const float* __restrict__ b_ro,
    float* __restrict__ out)
{
    const int b = blockIdx.x, tid = threadIdx.x;
    __shared__ float h[HH];
    __shared__ float hnew[HH];
    __shared__ float xin[414 + 2];
    __shared__ float gi[768];
    __shared__ float gh[768];
    __shared__ float xhat[DD];
    const float bih = b_ih[tid], bhh = b_hh[tid];
    const float bro = (tid < DD) ? b_ro[tid] : 0.f;
    if (tid < HH) h[tid] = 0.f;
    if (tid < DD) xhat[tid] = bro;
    __syncthreads();
    const float* xb = x + (size_t)b * SS * DD;
    const float* mb = mask + (size_t)b * SS * DD;
    float* ob = out + (size_t)b * SS * DD;
    for (int t = 0; t < SS; ++t) {
        if (tid < DD) ob[t * DD + tid] = xhat[tid];
        if (t == SS - 1) break;
        if (tid < DD) {
            float m = mb[t * DD + tid], xv = xb[t * DD + tid];
            xin[tid] = (m > 0.5f) ? xv : xhat[tid];
            xin[DD + tid] = m;
        }
        __syncthreads();
        float accI = bih, accH = bhh;
        const float* wi = W_ih + (size_t)tid * 414;
        for (int k = 0; k < 414; ++k) accI += wi[k] * xin[k];
        const float* wh = W_hh + (size_t)tid * HH;
        for (int k = 0; k < HH; ++k) accH += wh[k] * h[k];
        gi[tid] = accI; gh[tid] = accH;
        __syncthreads();
        if (tid < HH) {
            float r = 1.f / (1.f + __expf(-(gi[tid] + gh[tid])));
            float z = 1.f / (1.f + __expf(-(gi[HH + tid] + gh[HH + tid])));
            float n = tanhf(gi[2 * HH + tid] + r * gh[2 * HH + tid]);
            hnew[tid] = (1.f - z) * n + z * h[tid];
        }
        __syncthreads();
        if (tid < DD) {
            float acc = bro;
            const float* wr = W_ro + (size_t)tid * HH;
            for (int k = 0; k < HH; ++k) acc += wr[k] * hnew[k];
            xhat[tid] = acc;
        }
        if (tid < HH) h[tid] = hnew[tid];
        __syncthreads();
    }
}

extern "C" void kernel_launch(void* const* d_in, const int* in_sizes, int n_in,
                              void* d_out, int out_size, void* d_ws, size_t ws_size,
                              hipStream_t stream) {
    const float* x    = (const float*)d_in[0];
    const float* mask = (const float*)d_in[1];
    const float* W_ih = (const float*)d_in[2];
    const float* W_hh = (const float*)d_in[3];
    const float* b_ih = (const float*)d_in[4];
    const float* b_hh = (const float*)d_in[5];
    const float* W_ro = (const float*)d_in[6];
    const float* b_ro = (const float*)d_in[7];
    float* out = (float*)d_out;
    float* ws  = (float*)d_ws;

    if (ws_size >= WS_NEED6) {
        hipLaunchKernelGGL(rnn_init6, dim3(64), dim3(256), 0, stream, ws);
        hipLaunchKernelGGL(rnn_persist15, dim3(NWG), dim3(512), 0, stream,
                           x, mask, W_ih, W_hh, b_ih, b_hh, W_ro, b_ro, ws, out);
        hipLaunchKernelGGL(out_transpose, dim3(SS), dim3(256), 0, stream,
                           ws + BUF_FLOATS + FLAG_U32, out);
    } else if (ws_size >= V3_WS_FULL) {
        hipLaunchKernelGGL(v3_init, dim3(32), dim3(256), 0, stream, ws);
        hipLaunchKernelGGL((v3_persist<true>), dim3(NWG), dim3(256), 0, stream,
                           x, mask, W_ih, W_hh, b_ih, b_hh, W_ro, b_ro, ws, out);
        hipLaunchKernelGGL(out_transpose, dim3(SS), dim3(256), 0, stream,
                           ws + V3_ACT + V3_FLAGS, out);
    } else if (ws_size >= V3_WS_SMALL) {
        hipLaunchKernelGGL(v3_init, dim3(32), dim3(256), 0, stream, ws);
        hipLaunchKernelGGL((v3_persist<false>), dim3(NWG), dim3(256), 0, stream,
                           x, mask, W_ih, W_hh, b_ih, b_hh, W_ro, b_ro, ws, out);
    } else {
        hipLaunchKernelGGL(rnn_fallback, dim3(BB), dim3(768), 0, stream,
                           x, mask, W_ih, W_hh, b_ih, b_hh, W_ro, b_ro, out);
    }
}